// Round 9
// baseline (502.969 us; speedup 1.0000x reference)
//
#include <hip/hip_runtime.h>
#include <cstdint>
#include <cstddef>

using f16   = _Float16;
using f16x4 = __attribute__((ext_vector_type(4))) _Float16;
using f16x8 = __attribute__((ext_vector_type(8))) _Float16;
using f32x4 = __attribute__((ext_vector_type(4))) float;

__device__ __forceinline__ f32x4 mfma16(f16x8 a, f16x8 b, f32x4 c) {
  return __builtin_amdgcn_mfma_f32_16x16x32_f16(a, b, c, 0, 0, 0);
}

__device__ __forceinline__ void gld16(const f16* g, f16* l) {
  __builtin_amdgcn_global_load_lds(
      (__attribute__((address_space(1))) void*)g,
      (__attribute__((address_space(3))) void*)l, 16, 0, 0);
}

constexpr int BATCH = 2, SEQL = 2048, HID = 1024, NH = 16, DH = 64;
constexpr int TOK = BATCH * SEQL;   // 4096
constexpr int NQKV = 3 * HID;       // 3072
constexpr int NBLK = 512;           // 2 blocks/CU x 256 CUs, exact capacity

// Software grid barrier (sense-reversing, device scope). Safe because the
// grid is exactly co-resident: 512 blocks, __launch_bounds__(256,2),
// LDS 64KB/block (128KB/CU <= 160), VGPR forced <=128.
__device__ __forceinline__ void gbar(unsigned* bar) {
  __syncthreads();
  if (threadIdx.x == 0) {
    __threadfence();   // flush my writes device-wide (cross-XCD)
    unsigned gen = __hip_atomic_load(bar + 1, __ATOMIC_ACQUIRE,
                                     __HIP_MEMORY_SCOPE_AGENT);
    unsigned arr = __hip_atomic_fetch_add(bar, 1u, __ATOMIC_ACQ_REL,
                                          __HIP_MEMORY_SCOPE_AGENT);
    if (arr == NBLK - 1) {
      __hip_atomic_store(bar, 0u, __ATOMIC_RELAXED, __HIP_MEMORY_SCOPE_AGENT);
      __hip_atomic_fetch_add(bar + 1, 1u, __ATOMIC_RELEASE,
                             __HIP_MEMORY_SCOPE_AGENT);
    } else {
      while (__hip_atomic_load(bar + 1, __ATOMIC_ACQUIRE,
                               __HIP_MEMORY_SCOPE_AGENT) == gen)
        __builtin_amdgcn_s_sleep(8);
    }
    __threadfence();
  }
  __syncthreads();
}

// ---------------------------------------------------------------- fused
// ONE kernel, 4 phases separated by grid barriers, replacing 5 dispatches
// (the ~50-90us of inter-dispatch overhead is the target; per-phase bodies
// are copied verbatim from the proven standalone kernels).
__global__ __launch_bounds__(256, 2) void k_fused(
    const float* __restrict__ x,  const float* __restrict__ Wq,
    const float* __restrict__ bq, const float* __restrict__ Wk,
    const float* __restrict__ bk, const float* __restrict__ Wv,
    const float* __restrict__ bv, const float* __restrict__ Wo,
    const float* __restrict__ bo, float* __restrict__ out,
    f16* __restrict__ xh, f16* __restrict__ WT, f16* __restrict__ WoT,
    f16* __restrict__ Qh, f16* __restrict__ Kh, f16* __restrict__ Vp,
    f16* __restrict__ Ao, unsigned* __restrict__ bar) {
  __shared__ __attribute__((aligned(16))) char smem[65536];
  int bid = blockIdx.x;
  int tid = threadIdx.x;

  // ============ phase A: convert x to f16 + transpose weights ============
  {
    float (*tile)[33] = (float(*)[33])smem;
    for (int j = bid; j < 8192; j += NBLK) {
      if (j < 4096) {            // convert chunk (1024 f32)
        int i = j * 1024 + tid * 4;
        float4 v = *(const float4*)(x + i);
        f16x4 o = { (f16)v.x, (f16)v.y, (f16)v.z, (f16)v.w };
        *(f16x4*)(xh + i) = o;
      } else {                   // transpose 32x32 tile
        int t = j - 4096;
        int mat = t >> 10, rem = t & 1023;
        int in0 = (rem >> 5) * 32, out0 = (rem & 31) * 32;
        const float* W = (mat == 0) ? Wq : (mat == 1) ? Wk
                        : (mat == 2) ? Wv : Wo;
        int c = tid & 31, r8 = tid >> 5;
        __syncthreads();         // LDS reuse vs previous job
#pragma unroll
        for (int i = 0; i < 4; i++) {
          int r = r8 + i * 8;
          tile[r][c] = W[(size_t)(in0 + r) * HID + out0 + c];
        }
        __syncthreads();
#pragma unroll
        for (int i = 0; i < 4; i++) {
          int r = r8 + i * 8;
          f16 v = (f16)tile[c][r];
          if (mat == 3) WoT[(size_t)(out0 + r) * HID + in0 + c] = v;
          else          WT[(size_t)(mat * HID + out0 + r) * HID + in0 + c] = v;
        }
      }
    }
  }
  gbar(bar);

  // ============ phase B: QKV GEMM, 768 tiles of 128x128, BK=32 ============
  // V stored TRANSPOSED [d][key'] with 16x16-layout key permutation
  // key' = (k&~31)|((k&12)<<1)|((k>>2)&4)|(k&3) for the attn phase.
  {
    f16* Ash = (f16*)smem;
    f16* Bsh = Ash + 128 * 32;
    int w = tid >> 6, lane = tid & 63, lr = lane & 15, lq = lane >> 4;
    int wm = w >> 1, wn = w & 1;
    int row0 = tid >> 2, seg0 = tid & 3;
    int row1 = (256 + tid) >> 2;
    for (int t = bid; t < 768; t += NBLK) {
      int m0 = (t & 31) * 128, n0 = (t >> 5) * 128;
      f32x4 acc[4][4];
#pragma unroll
      for (int i = 0; i < 4; i++)
#pragma unroll
        for (int j = 0; j < 4; j++) acc[i][j] = (f32x4){0.f, 0.f, 0.f, 0.f};

      const f16* Ag0 = xh + (size_t)(m0 + row0) * HID + seg0 * 8;
      const f16* Ag1 = xh + (size_t)(m0 + row1) * HID + seg0 * 8;
      const f16* Bg0 = WT + (size_t)(n0 + row0) * HID + seg0 * 8;
      const f16* Bg1 = WT + (size_t)(n0 + row1) * HID + seg0 * 8;

      for (int k0 = 0; k0 < HID; k0 += 32) {
        __syncthreads();
        gld16(Ag0 + k0, Ash + tid * 8);
        gld16(Ag1 + k0, Ash + (256 + tid) * 8);
        gld16(Bg0 + k0, Bsh + tid * 8);
        gld16(Bg1 + k0, Bsh + (256 + tid) * 8);
        __syncthreads();
        f16x8 af[4], bfr[4];
#pragma unroll
        for (int mt = 0; mt < 4; mt++)
          af[mt] = *(const f16x8*)(Ash + (wm * 64 + mt * 16 + lr) * 32 + lq * 8);
#pragma unroll
        for (int nt = 0; nt < 4; nt++)
          bfr[nt] = *(const f16x8*)(Bsh + (wn * 64 + nt * 16 + lr) * 32 + lq * 8);
#pragma unroll
        for (int mt = 0; mt < 4; mt++)
#pragma unroll
          for (int nt = 0; nt < 4; nt++)
            acc[mt][nt] = mfma16(af[mt], bfr[nt], acc[mt][nt]);
      }

#pragma unroll
      for (int nt = 0; nt < 4; nt++) {
        int o = n0 + wn * 64 + nt * 16 + lr;
        int sec = o >> 10, o1 = o & 1023, hh = o1 >> 6, dd = o1 & 63;
        float bias = (sec == 0) ? bq[o1] : (sec == 1) ? bk[o1] : bv[o1];
#pragma unroll
        for (int mt = 0; mt < 4; mt++) {
          int t0 = m0 + wm * 64 + mt * 16 + lq * 4;
          int b = t0 >> 11, s0 = t0 & (SEQL - 1);
          size_t bh = (size_t)(b * NH + hh);
          if (sec == 2) {
            f16x4 pv = { (f16)(acc[mt][nt][0] + bias),
                         (f16)(acc[mt][nt][1] + bias),
                         (f16)(acc[mt][nt][2] + bias),
                         (f16)(acc[mt][nt][3] + bias) };
            int pb = (s0 & ~31) | ((s0 & 12) << 1) | ((s0 >> 2) & 4);
            *(f16x4*)(Vp + (bh * DH + dd) * SEQL + pb) = pv;  // V^T permuted
          } else {
            f16* dst = (sec == 0) ? Qh : Kh;
#pragma unroll
            for (int r = 0; r < 4; r++)
              dst[(bh * SEQL + s0 + r) * DH + dd] = (f16)(acc[mt][nt][r] + bias);
          }
        }
      }
    }
  }
  gbar(bar);

  // ============ phase C: attention (round-4 proven body) ============
  // bh = bid&31 -> id%8 = bh%8 keeps K/V L2-resident per XCD.
  {
    int bh = bid & 31;
    int qblk = bid >> 5;
    int b = bh >> 4, h = bh & 15;
    int w = tid >> 6;          // 0..3
    int g = w >> 1;            // key-half group (compute role)
    int wq = w & 1;            // q-wave within group (64 q)
    int lane = tid & 63, lr = lane & 15, lq = lane >> 4;
    f16* sh = (f16*)smem;      // [group][buf][K|V] linear 64x64 tiles, 64KB

    f16x8 qf[4][2];
#pragma unroll
    for (int qt = 0; qt < 4; qt++) {
      const f16* Qbase =
          Qh + ((size_t)bh * SEQL + qblk * 128 + wq * 64 + qt * 16 + lr) * DH;
#pragma unroll
      for (int ks = 0; ks < 2; ks++) {
        qf[qt][ks] = *(const f16x8*)(Qbase + ks * 32 + lq * 8);
        qf[qt][ks] = qf[qt][ks] * (f16)0.18033688f;  // 1/8 * log2(e)
      }
    }

    f32x4 O[4][4];
#pragma unroll
    for (int qt = 0; qt < 4; qt++)
#pragma unroll
      for (int dt = 0; dt < 4; dt++) O[qt][dt] = (f32x4){0.f, 0.f, 0.f, 0.f};
    float lsum[4] = {0.f, 0.f, 0.f, 0.f};

    int sg = w >> 1, kv = w & 1;
    int srow8 = lane >> 3;
    int scol = ((lane & 7) ^ srow8) * 8;   // inverse-swizzled global col
    const f16* sgl;
    size_t pstride, kbstride;
    if (kv == 0) {
      sgl = Kh + ((size_t)bh * SEQL + sg * 1024 + srow8) * DH + scol;
      pstride = (size_t)8 * DH;
      kbstride = (size_t)64 * DH;
    } else {
      sgl = Vp + ((size_t)bh * DH + srow8) * SEQL + sg * 1024 + scol;
      pstride = (size_t)8 * SEQL;
      kbstride = (size_t)64;
    }
    f16* sdst0 = sh + ((sg * 2 + 0) * 2 + kv) * 4096 + lane * 8;
    f16* sdst1 = sh + ((sg * 2 + 1) * 2 + kv) * 4096 + lane * 8;

    int swz = lr & 7;
    int c0 = ((0 * 4 + lq) ^ swz) * 8;
    int c1 = ((1 * 4 + lq) ^ swz) * 8;

#pragma unroll
    for (int p8 = 0; p8 < 8; p8++) gld16(sgl + p8 * pstride, sdst0 + p8 * 512);

    for (int kb = 0; kb < 16; kb++) {
      __syncthreads();
      if (kb < 15) {
        const f16* src = sgl + (size_t)(kb + 1) * kbstride;
        f16* sd = ((kb + 1) & 1) ? sdst1 : sdst0;
#pragma unroll
        for (int p8 = 0; p8 < 8; p8++) gld16(src + p8 * pstride, sd + p8 * 512);
      }

      const f16* Kp = sh + ((g * 2 + (kb & 1)) * 2 + 0) * 4096;
      const f16* Vq = Kp + 4096;

      f32x4 sacc[4][4];
#pragma unroll
      for (int qt = 0; qt < 4; qt++)
#pragma unroll
        for (int kt = 0; kt < 4; kt++) sacc[qt][kt] = (f32x4){0.f, 0.f, 0.f, 0.f};
      __builtin_amdgcn_s_setprio(1);
#pragma unroll
      for (int ks = 0; ks < 2; ks++) {
        int kc = ks ? c1 : c0;
#pragma unroll
        for (int kt = 0; kt < 4; kt++) {
          f16x8 kf = *(const f16x8*)(Kp + (kt * 16 + lr) * 64 + kc);
          sacc[0][kt] = mfma16(kf, qf[0][ks], sacc[0][kt]);
          sacc[1][kt] = mfma16(kf, qf[1][ks], sacc[1][kt]);
          sacc[2][kt] = mfma16(kf, qf[2][ks], sacc[2][kt]);
          sacc[3][kt] = mfma16(kf, qf[3][ks], sacc[3][kt]);
        }
      }
      __builtin_amdgcn_s_setprio(0);

      f16x8 pf[4][2];
#pragma unroll
      for (int qt = 0; qt < 4; qt++) {
        float part = 0.f;
#pragma unroll
        for (int kt = 0; kt < 4; kt++) {
          float p0 = __builtin_amdgcn_exp2f(sacc[qt][kt][0]);
          float p1 = __builtin_amdgcn_exp2f(sacc[qt][kt][1]);
          float p2 = __builtin_amdgcn_exp2f(sacc[qt][kt][2]);
          float p3 = __builtin_amdgcn_exp2f(sacc[qt][kt][3]);
          part += (p0 + p1) + (p2 + p3);
          int s = kt >> 1, off = (kt & 1) * 4;
          pf[qt][s][off + 0] = (f16)p0; pf[qt][s][off + 1] = (f16)p1;
          pf[qt][s][off + 2] = (f16)p2; pf[qt][s][off + 3] = (f16)p3;
        }
        lsum[qt] += part;
      }

      __builtin_amdgcn_s_setprio(1);
#pragma unroll
      for (int s = 0; s < 2; s++) {
        int vc = s ? c1 : c0;
#pragma unroll
        for (int dt = 0; dt < 4; dt++) {
          f16x8 vf = *(const f16x8*)(Vq + (dt * 16 + lr) * 64 + vc);
          O[0][dt] = mfma16(vf, pf[0][s], O[0][dt]);
          O[1][dt] = mfma16(vf, pf[1][s], O[1][dt]);
          O[2][dt] = mfma16(vf, pf[2][s], O[2][dt]);
          O[3][dt] = mfma16(vf, pf[3][s], O[3][dt]);
        }
      }
      __builtin_amdgcn_s_setprio(0);
    }

    // merge the two key-halves via LDS (slot-XOR: conflict-free)
    __syncthreads();
    float* mrg = (float*)sh;          // [128 q][16 slots of 16B]
    float* pls = mrg + 128 * 64;      // [128 q][4 lq]
    if (g == 1) {
#pragma unroll
      for (int qt = 0; qt < 4; qt++) {
        int ql = wq * 64 + qt * 16 + lr;
#pragma unroll
        for (int dt = 0; dt < 4; dt++) {
          int slot = (dt * 4 + lq) ^ lr;
          *(f32x4*)(mrg + ql * 64 + slot * 4) = O[qt][dt];
        }
        pls[ql * 4 + lq] = lsum[qt];
      }
    }
    __syncthreads();
    if (g == 0) {
#pragma unroll
      for (int qt = 0; qt < 4; qt++) {
        int ql = wq * 64 + qt * 16 + lr;
        float ls = lsum[qt] + pls[ql * 4 + lq];
        float l1 = ls + __shfl_xor(ls, 16);
        float ltot = l1 + __shfl_xor(l1, 32);
        float inv = 1.0f / ltot;
        int q = qblk * 128 + ql;
        f16* dst = Ao + ((size_t)b * SEQL + q) * HID + h * DH;
#pragma unroll
        for (int dt = 0; dt < 4; dt++) {
          int slot = (dt * 4 + lq) ^ lr;
          f32x4 po = *(const f32x4*)(mrg + ql * 64 + slot * 4);
          f16x4 o = { (f16)((O[qt][dt][0] + po[0]) * inv),
                      (f16)((O[qt][dt][1] + po[1]) * inv),
                      (f16)((O[qt][dt][2] + po[2]) * inv),
                      (f16)((O[qt][dt][3] + po[3]) * inv) };
          *(f16x4*)(dst + dt * 16 + lq * 4) = o;
        }
      }
    }
  }
  gbar(bar);

  // ============ phase D: out GEMM, 512 tiles of 128x64 ============
  {
    f16* Ash = (f16*)smem;
    f16* Bsh = Ash + 128 * 32;
    int w = tid >> 6, lane = tid & 63, lr = lane & 15, lq = lane >> 4;
    int wm = w >> 1, wn = w & 1;
    int m0 = (bid & 31) * 128, n0 = (bid >> 5) * 64;
    f32x4 acc[4][2];
#pragma unroll
    for (int i = 0; i < 4; i++)
#pragma unroll
      for (int j = 0; j < 2; j++) acc[i][j] = (f32x4){0.f, 0.f, 0.f, 0.f};

    int row0 = tid >> 2, seg0 = tid & 3;
    int row1 = (256 + tid) >> 2;
    const f16* Ag0 = Ao + (size_t)(m0 + row0) * HID + seg0 * 8;
    const f16* Ag1 = Ao + (size_t)(m0 + row1) * HID + seg0 * 8;
    const f16* Bg0 = WoT + (size_t)(n0 + row0) * HID + seg0 * 8;

    for (int k0 = 0; k0 < HID; k0 += 32) {
      __syncthreads();
      gld16(Ag0 + k0, Ash + tid * 8);
      gld16(Ag1 + k0, Ash + (256 + tid) * 8);
      gld16(Bg0 + k0, Bsh + tid * 8);
      __syncthreads();
      f16x8 af[4], bfr[2];
#pragma unroll
      for (int mt = 0; mt < 4; mt++)
        af[mt] = *(const f16x8*)(Ash + (wm * 64 + mt * 16 + lr) * 32 + lq * 8);
#pragma unroll
      for (int nt = 0; nt < 2; nt++)
        bfr[nt] = *(const f16x8*)(Bsh + (wn * 32 + nt * 16 + lr) * 32 + lq * 8);
#pragma unroll
      for (int mt = 0; mt < 4; mt++)
#pragma unroll
        for (int nt = 0; nt < 2; nt++)
          acc[mt][nt] = mfma16(af[mt], bfr[nt], acc[mt][nt]);
    }

#pragma unroll
    for (int nt = 0; nt < 2; nt++) {
      int o = n0 + wn * 32 + nt * 16 + lr;
      float bias = bo[o];
#pragma unroll
      for (int mt = 0; mt < 4; mt++) {
        int t0 = m0 + wm * 64 + mt * 16 + lq * 4;
#pragma unroll
        for (int r = 0; r < 4; r++)
          out[(size_t)(t0 + r) * HID + o] = acc[mt][nt][r] + bias;
      }
    }
  }
}

// ---------------------------------------------------------------- launch
extern "C" void kernel_launch(void* const* d_in, const int* in_sizes, int n_in,
                              void* d_out, int out_size, void* d_ws, size_t ws_size,
                              hipStream_t stream) {
  const float* x  = (const float*)d_in[0];
  const float* Wq = (const float*)d_in[1];
  const float* bq = (const float*)d_in[2];
  const float* Wk = (const float*)d_in[3];
  const float* bk = (const float*)d_in[4];
  const float* Wv = (const float*)d_in[5];
  const float* bv = (const float*)d_in[6];
  const float* Wo = (const float*)d_in[7];
  const float* bo = (const float*)d_in[8];

  char* ws = (char*)d_ws;
  f16* xh  = (f16*)(ws + 0);                       //  8 MiB
  f16* WT  = (f16*)(ws + 8388608);                 //  6 MiB
  f16* WoT = (f16*)(ws + 14680064);                //  2 MiB
  f16* Qh  = (f16*)(ws + 16777216);                //  8 MiB [bh][s][d]
  f16* Kh  = (f16*)(ws + 25165824);                //  8 MiB [bh][s][d]
  f16* Vp  = (f16*)(ws + 33554432);                //  8 MiB [bh][d][key']
  f16* Ao  = (f16*)(ws + 41943040);                //  8 MiB [b][s][h*dv]
  unsigned* bar = (unsigned*)(ws + 50331648);      //  grid barrier state

  // workspace is re-poisoned by the harness each iteration -> zero the
  // barrier words inside the captured graph (memset node; allowed API).
  hipMemsetAsync(bar, 0, 64, stream);
  k_fused<<<NBLK, 256, 0, stream>>>(x, Wq, bq, Wk, bk, Wv, bv, Wo, bo,
                                    (float*)d_out, xh, WT, WoT, Qh, Kh, Vp,
                                    Ao, bar);
}

// Round 10
// 315.805 us; speedup vs baseline: 1.5927x; 1.5927x over previous
//
#include <hip/hip_runtime.h>
#include <cstdint>
#include <cstddef>

using f16   = _Float16;
using f16x4 = __attribute__((ext_vector_type(4))) _Float16;
using f16x8 = __attribute__((ext_vector_type(8))) _Float16;
using f32x4 = __attribute__((ext_vector_type(4))) float;

__device__ __forceinline__ f32x4 mfma16(f16x8 a, f16x8 b, f32x4 c) {
  return __builtin_amdgcn_mfma_f32_16x16x32_f16(a, b, c, 0, 0, 0);
}

__device__ __forceinline__ void gld16(const f16* g, f16* l) {
  __builtin_amdgcn_global_load_lds(
      (__attribute__((address_space(1))) void*)g,
      (__attribute__((address_space(3))) void*)l, 16, 0, 0);
}

constexpr int BATCH = 2, SEQL = 2048, HID = 1024, NH = 16, DH = 64;
constexpr int TOK = BATCH * SEQL;   // 4096
constexpr int NQKV = 3 * HID;       // 3072
constexpr int NBLK = 512;           // 2 blocks/CU x 256 CUs, exact capacity

// Software grid barrier. ROUND-10 FIX: the round-9 version spun on ACQUIRE
// agent loads -> buffer_inv of the XCD L2 EVERY spin iteration by 512 blocks
// -> global cache poisoning (FETCH 6x, hbm pinned 307GB/s, 10x slowdown).
// Now: spin on RELAXED loads (sc-bypass, no invalidation); ONE acquire fence
// after the spin; release folded into the arrival RMW.
__device__ __forceinline__ void gbar(unsigned* bar) {
  __syncthreads();
  if (threadIdx.x == 0) {
    unsigned gen = __hip_atomic_load(bar + 1, __ATOMIC_RELAXED,
                                     __HIP_MEMORY_SCOPE_AGENT);
    unsigned arr = __hip_atomic_fetch_add(bar, 1u, __ATOMIC_RELEASE,
                                          __HIP_MEMORY_SCOPE_AGENT);
    if (arr == NBLK - 1) {
      __hip_atomic_store(bar, 0u, __ATOMIC_RELAXED, __HIP_MEMORY_SCOPE_AGENT);
      __hip_atomic_store(bar + 1, gen + 1u, __ATOMIC_RELEASE,
                         __HIP_MEMORY_SCOPE_AGENT);
    } else {
      while (__hip_atomic_load(bar + 1, __ATOMIC_RELAXED,
                               __HIP_MEMORY_SCOPE_AGENT) == gen)
        __builtin_amdgcn_s_sleep(16);
    }
    __builtin_amdgcn_fence(__ATOMIC_ACQUIRE, "agent");  // ONE invalidate
  }
  __syncthreads();
}

// ---------------------------------------------------------------- fused
// ONE kernel, 4 phases separated by grid barriers, replacing 5 dispatches.
// Phase bodies are the proven standalone kernels; phase B retiled to 512
// tiles of 128x192 (exact grid, no 2x imbalance).
__global__ __launch_bounds__(256, 2) void k_fused(
    const float* __restrict__ x,  const float* __restrict__ Wq,
    const float* __restrict__ bq, const float* __restrict__ Wk,
    const float* __restrict__ bk, const float* __restrict__ Wv,
    const float* __restrict__ bv, const float* __restrict__ Wo,
    const float* __restrict__ bo, float* __restrict__ out,
    f16* __restrict__ xh, f16* __restrict__ WT, f16* __restrict__ WoT,
    f16* __restrict__ Qh, f16* __restrict__ Kh, f16* __restrict__ Vp,
    f16* __restrict__ Ao, unsigned* __restrict__ bar) {
  __shared__ __attribute__((aligned(16))) char smem[65536];
  int bid = blockIdx.x;
  int tid = threadIdx.x;

  // ============ phase A: convert x to f16 + transpose weights ============
  {
    float (*tile)[33] = (float(*)[33])smem;
    for (int j = bid; j < 8192; j += NBLK) {
      if (j < 4096) {            // convert chunk (1024 f32)
        int i = j * 1024 + tid * 4;
        float4 v = *(const float4*)(x + i);
        f16x4 o = { (f16)v.x, (f16)v.y, (f16)v.z, (f16)v.w };
        *(f16x4*)(xh + i) = o;
      } else {                   // transpose 32x32 tile
        int t = j - 4096;
        int mat = t >> 10, rem = t & 1023;
        int in0 = (rem >> 5) * 32, out0 = (rem & 31) * 32;
        const float* W = (mat == 0) ? Wq : (mat == 1) ? Wk
                        : (mat == 2) ? Wv : Wo;
        int c = tid & 31, r8 = tid >> 5;
        __syncthreads();         // LDS reuse vs previous job
#pragma unroll
        for (int i = 0; i < 4; i++) {
          int r = r8 + i * 8;
          tile[r][c] = W[(size_t)(in0 + r) * HID + out0 + c];
        }
        __syncthreads();
#pragma unroll
        for (int i = 0; i < 4; i++) {
          int r = r8 + i * 8;
          f16 v = (f16)tile[c][r];
          if (mat == 3) WoT[(size_t)(out0 + r) * HID + in0 + c] = v;
          else          WT[(size_t)(mat * HID + out0 + r) * HID + in0 + c] = v;
        }
      }
    }
  }
  gbar(bar);

  // ============ phase B: QKV GEMM, 512 tiles of 128x192, BK=32 ============
  // V stored TRANSPOSED [d][key'] with 16x16-layout key permutation
  // key' = (k&~31)|((k&12)<<1)|((k>>2)&4)|(k&3) for the attn phase.
  {
    f16* Ash = (f16*)smem;                  //  8 KB
    f16* Bsh = Ash + 128 * 32;              // 12 KB
    int w = tid >> 6, lane = tid & 63, lr = lane & 15, lq = lane >> 4;
    int wm = w >> 1, wn = w & 1;
    int row0 = tid >> 2, seg0 = tid & 3;
    int row1 = (256 + tid) >> 2;
    int m0 = (bid & 31) * 128, n0 = (bid >> 5) * 192;
    f32x4 acc[4][6];
#pragma unroll
    for (int i = 0; i < 4; i++)
#pragma unroll
      for (int j = 0; j < 6; j++) acc[i][j] = (f32x4){0.f, 0.f, 0.f, 0.f};

    const f16* Ag0 = xh + (size_t)(m0 + row0) * HID + seg0 * 8;
    const f16* Ag1 = xh + (size_t)(m0 + row1) * HID + seg0 * 8;
    const f16* Bg0 = WT + (size_t)(n0 + row0) * HID + seg0 * 8;
    const f16* Bg1 = WT + (size_t)(n0 + row0 + 64) * HID + seg0 * 8;
    const f16* Bg2 = WT + (size_t)(n0 + row0 + 128) * HID + seg0 * 8;

    for (int k0 = 0; k0 < HID; k0 += 32) {
      __syncthreads();
      gld16(Ag0 + k0, Ash + tid * 8);
      gld16(Ag1 + k0, Ash + (256 + tid) * 8);
      gld16(Bg0 + k0, Bsh + tid * 8);
      gld16(Bg1 + k0, Bsh + (256 + tid) * 8);
      gld16(Bg2 + k0, Bsh + (512 + tid) * 8);
      __syncthreads();
      f16x8 af[4], bfr[6];
#pragma unroll
      for (int mt = 0; mt < 4; mt++)
        af[mt] = *(const f16x8*)(Ash + (wm * 64 + mt * 16 + lr) * 32 + lq * 8);
#pragma unroll
      for (int nt = 0; nt < 6; nt++)
        bfr[nt] = *(const f16x8*)(Bsh + (wn * 96 + nt * 16 + lr) * 32 + lq * 8);
#pragma unroll
      for (int mt = 0; mt < 4; mt++)
#pragma unroll
        for (int nt = 0; nt < 6; nt++)
          acc[mt][nt] = mfma16(af[mt], bfr[nt], acc[mt][nt]);
    }

#pragma unroll
    for (int nt = 0; nt < 6; nt++) {
      int o = n0 + wn * 96 + nt * 16 + lr;
      int sec = o >> 10, o1 = o & 1023, hh = o1 >> 6, dd = o1 & 63;
      float bias = (sec == 0) ? bq[o1] : (sec == 1) ? bk[o1] : bv[o1];
#pragma unroll
      for (int mt = 0; mt < 4; mt++) {
        int t0 = m0 + wm * 64 + mt * 16 + lq * 4;
        int b = t0 >> 11, s0 = t0 & (SEQL - 1);
        size_t bh = (size_t)(b * NH + hh);
        if (sec == 2) {
          f16x4 pv = { (f16)(acc[mt][nt][0] + bias),
                       (f16)(acc[mt][nt][1] + bias),
                       (f16)(acc[mt][nt][2] + bias),
                       (f16)(acc[mt][nt][3] + bias) };
          int pb = (s0 & ~31) | ((s0 & 12) << 1) | ((s0 >> 2) & 4);
          *(f16x4*)(Vp + (bh * DH + dd) * SEQL + pb) = pv;  // V^T permuted
        } else {
          f16* dst = (sec == 0) ? Qh : Kh;
#pragma unroll
          for (int r = 0; r < 4; r++)
            dst[(bh * SEQL + s0 + r) * DH + dd] = (f16)(acc[mt][nt][r] + bias);
        }
      }
    }
  }
  gbar(bar);

  // ============ phase C: attention (round-4 proven body) ============
  // bh = bid&31 -> id%8 = bh%8 keeps K/V L2-resident per XCD.
  {
    int bh = bid & 31;
    int qblk = bid >> 5;
    int b = bh >> 4, h = bh & 15;
    int w = tid >> 6;          // 0..3
    int g = w >> 1;            // key-half group (compute role)
    int wq = w & 1;            // q-wave within group (64 q)
    int lane = tid & 63, lr = lane & 15, lq = lane >> 4;
    f16* sh = (f16*)smem;      // [group][buf][K|V] linear 64x64 tiles, 64KB

    f16x8 qf[4][2];
#pragma unroll
    for (int qt = 0; qt < 4; qt++) {
      const f16* Qbase =
          Qh + ((size_t)bh * SEQL + qblk * 128 + wq * 64 + qt * 16 + lr) * DH;
#pragma unroll
      for (int ks = 0; ks < 2; ks++) {
        qf[qt][ks] = *(const f16x8*)(Qbase + ks * 32 + lq * 8);
        qf[qt][ks] = qf[qt][ks] * (f16)0.18033688f;  // 1/8 * log2(e)
      }
    }

    f32x4 O[4][4];
#pragma unroll
    for (int qt = 0; qt < 4; qt++)
#pragma unroll
      for (int dt = 0; dt < 4; dt++) O[qt][dt] = (f32x4){0.f, 0.f, 0.f, 0.f};
    float lsum[4] = {0.f, 0.f, 0.f, 0.f};

    int sg = w >> 1, kv = w & 1;
    int srow8 = lane >> 3;
    int scol = ((lane & 7) ^ srow8) * 8;   // inverse-swizzled global col
    const f16* sgl;
    size_t pstride, kbstride;
    if (kv == 0) {
      sgl = Kh + ((size_t)bh * SEQL + sg * 1024 + srow8) * DH + scol;
      pstride = (size_t)8 * DH;
      kbstride = (size_t)64 * DH;
    } else {
      sgl = Vp + ((size_t)bh * DH + srow8) * SEQL + sg * 1024 + scol;
      pstride = (size_t)8 * SEQL;
      kbstride = (size_t)64;
    }
    f16* sdst0 = sh + ((sg * 2 + 0) * 2 + kv) * 4096 + lane * 8;
    f16* sdst1 = sh + ((sg * 2 + 1) * 2 + kv) * 4096 + lane * 8;

    int swz = lr & 7;
    int c0 = ((0 * 4 + lq) ^ swz) * 8;
    int c1 = ((1 * 4 + lq) ^ swz) * 8;

#pragma unroll
    for (int p8 = 0; p8 < 8; p8++) gld16(sgl + p8 * pstride, sdst0 + p8 * 512);

    for (int kb = 0; kb < 16; kb++) {
      __syncthreads();
      if (kb < 15) {
        const f16* src = sgl + (size_t)(kb + 1) * kbstride;
        f16* sd = ((kb + 1) & 1) ? sdst1 : sdst0;
#pragma unroll
        for (int p8 = 0; p8 < 8; p8++) gld16(src + p8 * pstride, sd + p8 * 512);
      }

      const f16* Kp = sh + ((g * 2 + (kb & 1)) * 2 + 0) * 4096;
      const f16* Vq = Kp + 4096;

      f32x4 sacc[4][4];
#pragma unroll
      for (int qt = 0; qt < 4; qt++)
#pragma unroll
        for (int kt = 0; kt < 4; kt++) sacc[qt][kt] = (f32x4){0.f, 0.f, 0.f, 0.f};
      __builtin_amdgcn_s_setprio(1);
#pragma unroll
      for (int ks = 0; ks < 2; ks++) {
        int kc = ks ? c1 : c0;
#pragma unroll
        for (int kt = 0; kt < 4; kt++) {
          f16x8 kf = *(const f16x8*)(Kp + (kt * 16 + lr) * 64 + kc);
          sacc[0][kt] = mfma16(kf, qf[0][ks], sacc[0][kt]);
          sacc[1][kt] = mfma16(kf, qf[1][ks], sacc[1][kt]);
          sacc[2][kt] = mfma16(kf, qf[2][ks], sacc[2][kt]);
          sacc[3][kt] = mfma16(kf, qf[3][ks], sacc[3][kt]);
        }
      }
      __builtin_amdgcn_s_setprio(0);

      f16x8 pf[4][2];
#pragma unroll
      for (int qt = 0; qt < 4; qt++) {
        float part = 0.f;
#pragma unroll
        for (int kt = 0; kt < 4; kt++) {
          float p0 = __builtin_amdgcn_exp2f(sacc[qt][kt][0]);
          float p1 = __builtin_amdgcn_exp2f(sacc[qt][kt][1]);
          float p2 = __builtin_amdgcn_exp2f(sacc[qt][kt][2]);
          float p3 = __builtin_amdgcn_exp2f(sacc[qt][kt][3]);
          part += (p0 + p1) + (p2 + p3);
          int s = kt >> 1, off = (kt & 1) * 4;
          pf[qt][s][off + 0] = (f16)p0; pf[qt][s][off + 1] = (f16)p1;
          pf[qt][s][off + 2] = (f16)p2; pf[qt][s][off + 3] = (f16)p3;
        }
        lsum[qt] += part;
      }

      __builtin_amdgcn_s_setprio(1);
#pragma unroll
      for (int s = 0; s < 2; s++) {
        int vc = s ? c1 : c0;
#pragma unroll
        for (int dt = 0; dt < 4; dt++) {
          f16x8 vf = *(const f16x8*)(Vq + (dt * 16 + lr) * 64 + vc);
          O[0][dt] = mfma16(vf, pf[0][s], O[0][dt]);
          O[1][dt] = mfma16(vf, pf[1][s], O[1][dt]);
          O[2][dt] = mfma16(vf, pf[2][s], O[2][dt]);
          O[3][dt] = mfma16(vf, pf[3][s], O[3][dt]);
        }
      }
      __builtin_amdgcn_s_setprio(0);
    }

    // merge the two key-halves via LDS (slot-XOR: conflict-free)
    __syncthreads();
    float* mrg = (float*)sh;          // [128 q][16 slots of 16B]
    float* pls = mrg + 128 * 64;      // [128 q][4 lq]
    if (g == 1) {
#pragma unroll
      for (int qt = 0; qt < 4; qt++) {
        int ql = wq * 64 + qt * 16 + lr;
#pragma unroll
        for (int dt = 0; dt < 4; dt++) {
          int slot = (dt * 4 + lq) ^ lr;
          *(f32x4*)(mrg + ql * 64 + slot * 4) = O[qt][dt];
        }
        pls[ql * 4 + lq] = lsum[qt];
      }
    }
    __syncthreads();
    if (g == 0) {
#pragma unroll
      for (int qt = 0; qt < 4; qt++) {
        int ql = wq * 64 + qt * 16 + lr;
        float ls = lsum[qt] + pls[ql * 4 + lq];
        float l1 = ls + __shfl_xor(ls, 16);
        float ltot = l1 + __shfl_xor(l1, 32);
        float inv = 1.0f / ltot;
        int q = qblk * 128 + ql;
        f16* dst = Ao + ((size_t)b * SEQL + q) * HID + h * DH;
#pragma unroll
        for (int dt = 0; dt < 4; dt++) {
          int slot = (dt * 4 + lq) ^ lr;
          f32x4 po = *(const f32x4*)(mrg + ql * 64 + slot * 4);
          f16x4 o = { (f16)((O[qt][dt][0] + po[0]) * inv),
                      (f16)((O[qt][dt][1] + po[1]) * inv),
                      (f16)((O[qt][dt][2] + po[2]) * inv),
                      (f16)((O[qt][dt][3] + po[3]) * inv) };
          *(f16x4*)(dst + dt * 16 + lq * 4) = o;
        }
      }
    }
  }
  gbar(bar);

  // ============ phase D: out GEMM, 512 tiles of 128x64 ============
  {
    f16* Ash = (f16*)smem;
    f16* Bsh = Ash + 128 * 32;
    int w = tid >> 6, lane = tid & 63, lr = lane & 15, lq = lane >> 4;
    int wm = w >> 1, wn = w & 1;
    int m0 = (bid & 31) * 128, n0 = (bid >> 5) * 64;
    f32x4 acc[4][2];
#pragma unroll
    for (int i = 0; i < 4; i++)
#pragma unroll
      for (int j = 0; j < 2; j++) acc[i][j] = (f32x4){0.f, 0.f, 0.f, 0.f};

    int row0 = tid >> 2, seg0 = tid & 3;
    int row1 = (256 + tid) >> 2;
    const f16* Ag0 = Ao + (size_t)(m0 + row0) * HID + seg0 * 8;
    const f16* Ag1 = Ao + (size_t)(m0 + row1) * HID + seg0 * 8;
    const f16* Bg0 = WoT + (size_t)(n0 + row0) * HID + seg0 * 8;

    for (int k0 = 0; k0 < HID; k0 += 32) {
      __syncthreads();
      gld16(Ag0 + k0, Ash + tid * 8);
      gld16(Ag1 + k0, Ash + (256 + tid) * 8);
      gld16(Bg0 + k0, Bsh + tid * 8);
      __syncthreads();
      f16x8 af[4], bfr[2];
#pragma unroll
      for (int mt = 0; mt < 4; mt++)
        af[mt] = *(const f16x8*)(Ash + (wm * 64 + mt * 16 + lr) * 32 + lq * 8);
#pragma unroll
      for (int nt = 0; nt < 2; nt++)
        bfr[nt] = *(const f16x8*)(Bsh + (wn * 32 + nt * 16 + lr) * 32 + lq * 8);
#pragma unroll
      for (int mt = 0; mt < 4; mt++)
#pragma unroll
        for (int nt = 0; nt < 2; nt++)
          acc[mt][nt] = mfma16(af[mt], bfr[nt], acc[mt][nt]);
    }

#pragma unroll
    for (int nt = 0; nt < 2; nt++) {
      int o = n0 + wn * 32 + nt * 16 + lr;
      float bias = bo[o];
#pragma unroll
      for (int mt = 0; mt < 4; mt++) {
        int t0 = m0 + wm * 64 + mt * 16 + lq * 4;
#pragma unroll
        for (int r = 0; r < 4; r++)
          out[(size_t)(t0 + r) * HID + o] = acc[mt][nt][r] + bias;
      }
    }
  }
}

// ---------------------------------------------------------------- launch
extern "C" void kernel_launch(void* const* d_in, const int* in_sizes, int n_in,
                              void* d_out, int out_size, void* d_ws, size_t ws_size,
                              hipStream_t stream) {
  const float* x  = (const float*)d_in[0];
  const float* Wq = (const float*)d_in[1];
  const float* bq = (const float*)d_in[2];
  const float* Wk = (const float*)d_in[3];
  const float* bk = (const float*)d_in[4];
  const float* Wv = (const float*)d_in[5];
  const float* bv = (const float*)d_in[6];
  const float* Wo = (const float*)d_in[7];
  const float* bo = (const float*)d_in[8];

  char* ws = (char*)d_ws;
  f16* xh  = (f16*)(ws + 0);                       //  8 MiB
  f16* WT  = (f16*)(ws + 8388608);                 //  6 MiB
  f16* WoT = (f16*)(ws + 14680064);                //  2 MiB
  f16* Qh  = (f16*)(ws + 16777216);                //  8 MiB [bh][s][d]
  f16* Kh  = (f16*)(ws + 25165824);                //  8 MiB [bh][s][d]
  f16* Vp  = (f16*)(ws + 33554432);                //  8 MiB [bh][d][key']
  f16* Ao  = (f16*)(ws + 41943040);                //  8 MiB [b][s][h*dv]
  unsigned* bar = (unsigned*)(ws + 50331648);      //  grid barrier state

  // workspace is re-poisoned by the harness each iteration -> zero the
  // barrier words inside the captured graph (memset node; allowed API).
  hipMemsetAsync(bar, 0, 64, stream);
  k_fused<<<NBLK, 256, 0, stream>>>(x, Wq, bq, Wk, bk, Wv, bv, Wo, bo,
                                    (float*)d_out, xh, WT, WoT, Qh, Kh, Vp,
                                    Ao, bar);
}